// Round 7
// baseline (168.415 us; speedup 1.0000x reference)
//
#include <hip/hip_runtime.h>
#include <math.h>

#define S_ 2048
#define D_ 1024
#define HN_ 1024
#define B_ 4
#define M_ 8192
#define K1_ 3072
#define K3_ 1024
#define ITERS_ 10
#define DT_ 0.1f
#define PI_ 3.14159265358979323846f
#define TWOPI_ 6.28318530717958647692f
#define INV2PI_ 0.15915494309189533577f
#define SCALE_ 4096.0f
#define INVSC2_ (1.0f / 16777216.0f)   // 2^-24

typedef __attribute__((ext_vector_type(8))) _Float16 f16x8;
typedef __attribute__((ext_vector_type(4))) float f32x4;

// static scratch
__device__ ushort g_xs [(size_t)M_ * K1_];      // x split [a|a|b] fp16, scaled 4096
__device__ ushort g_WpT[(size_t)HN_ * K1_];     // Wp^T split [a|b|a] fp16, scaled 4096
__device__ float  g_ph [(size_t)B_ * HN_ * S_]; // phases f32 [b][hn][s]
__device__ ushort g_phh[(size_t)B_ * HN_ * S_]; // final phases fp16 [b][hn][s]
__device__ ushort g_phT[(size_t)M_ * HN_];      // phases fp16 [(b,s)][hn]
__device__ ushort g_WoT[(size_t)D_ * HN_];      // Wo^T fp16 [d][hn] (unscaled)

__device__ __forceinline__ ushort f2h(float f) {
    union { _Float16 h; ushort u; } v; v.h = (_Float16)f; return v.u;
}
__device__ __forceinline__ void split2s(float x, ushort& A, ushort& Bc) {
    const float xs = x * SCALE_;
    union { _Float16 h; ushort u; } va, vb;
    va.h = (_Float16)xs;
    const float r = xs - (float)va.h;   // exact
    vb.h = (_Float16)r;
    A = va.u; Bc = vb.u;
}
__device__ __forceinline__ void gload16(const void* g, void* l) {
    __builtin_amdgcn_global_load_lds(
        (const __attribute__((address_space(1))) void*)g,
        (__attribute__((address_space(3))) void*)l, 16, 0, 0);
}
__device__ __forceinline__ int pack2(ushort a, ushort b) {
    return (int)(unsigned)a | ((int)(unsigned)b << 16);
}

// ---------------------------------------------------------------------------
// prep kernels (unchanged, verified)
// ---------------------------------------------------------------------------
__global__ __launch_bounds__(256) void split_x(const float* __restrict__ X) {
    const int idx = blockIdx.x * 256 + threadIdx.x;
    const float4 v = ((const float4*)X)[idx];
    const int m  = idx >> 8;
    const int k4 = (idx & 255) * 4;
    ushort a[4], b[4];
    split2s(v.x, a[0], b[0]);
    split2s(v.y, a[1], b[1]);
    split2s(v.z, a[2], b[2]);
    split2s(v.w, a[3], b[3]);
    ushort* row = g_xs + (size_t)m * K1_ + k4;
    int2 oa; oa.x = pack2(a[0], a[1]); oa.y = pack2(a[2], a[3]);
    int2 ob; ob.x = pack2(b[0], b[1]); ob.y = pack2(b[2], b[3]);
    *(int2*)(row)        = oa;
    *(int2*)(row + 1024) = oa;
    *(int2*)(row + 2048) = ob;
}

__global__ __launch_bounds__(256) void splitT_Wp(const float* __restrict__ Wp) {
    __shared__ float t[64][68];
    const int k0 = blockIdx.x * 64;
    const int n0 = blockIdx.y * 64;
    const int r = threadIdx.x >> 2;
    const int c = (threadIdx.x & 3) * 16;
    const float* src = Wp + (size_t)(k0 + r) * HN_ + n0 + c;
    #pragma unroll
    for (int q = 0; q < 4; ++q)
        *(float4*)&t[r][c + 4 * q] = ((const float4*)src)[q];
    __syncthreads();
    ushort ha[16], hb[16];
    #pragma unroll
    for (int j = 0; j < 16; ++j)
        split2s(t[c + j][r], ha[j], hb[j]);
    int4 a0, a1, b0, b1;
    a0.x = pack2(ha[0], ha[1]);   a0.y = pack2(ha[2], ha[3]);
    a0.z = pack2(ha[4], ha[5]);   a0.w = pack2(ha[6], ha[7]);
    a1.x = pack2(ha[8], ha[9]);   a1.y = pack2(ha[10], ha[11]);
    a1.z = pack2(ha[12], ha[13]); a1.w = pack2(ha[14], ha[15]);
    b0.x = pack2(hb[0], hb[1]);   b0.y = pack2(hb[2], hb[3]);
    b0.z = pack2(hb[4], hb[5]);   b0.w = pack2(hb[6], hb[7]);
    b1.x = pack2(hb[8], hb[9]);   b1.y = pack2(hb[10], hb[11]);
    b1.z = pack2(hb[12], hb[13]); b1.w = pack2(hb[14], hb[15]);
    ushort* dst = g_WpT + (size_t)(n0 + r) * K1_ + k0 + c;
    *(int4*)(dst)            = a0; *(int4*)(dst + 8)        = a1;
    *(int4*)(dst + 1024)     = b0; *(int4*)(dst + 1032)     = b1;
    *(int4*)(dst + 2048)     = a0; *(int4*)(dst + 2056)     = a1;
}

__global__ __launch_bounds__(256) void castT_Wo(const float* __restrict__ Wo) {
    __shared__ float t[64][68];
    const int k0 = blockIdx.x * 64;   // hn
    const int n0 = blockIdx.y * 64;   // d
    const int r = threadIdx.x >> 2;
    const int c = (threadIdx.x & 3) * 16;
    const float* src = Wo + (size_t)(k0 + r) * D_ + n0 + c;
    #pragma unroll
    for (int q = 0; q < 4; ++q)
        *(float4*)&t[r][c + 4 * q] = ((const float4*)src)[q];
    __syncthreads();
    ushort h[16];
    #pragma unroll
    for (int j = 0; j < 16; ++j) h[j] = f2h(t[c + j][r]);
    ushort* dst = g_WoT + (size_t)(n0 + r) * HN_ + k0 + c;
    int4 o0, o1;
    o0.x = pack2(h[0], h[1]);   o0.y = pack2(h[2], h[3]);
    o0.z = pack2(h[4], h[5]);   o0.w = pack2(h[6], h[7]);
    o1.x = pack2(h[8], h[9]);   o1.y = pack2(h[10], h[11]);
    o1.z = pack2(h[12], h[13]); o1.w = pack2(h[14], h[15]);
    *(int4*)dst = o0;
    *(int4*)(dst + 8) = o1;
}

// ---------------------------------------------------------------------------
// MFMA main loop, BM=128 x BN=128, BK=64, 4 waves (2M x 2N), 256 threads.
// LDS: 2 buffers x 32KB (A 16KB + B 16KB) = 64KB -> 2 blocks/CU (the lever:
// an independent barrier group per CU fills pipes while the other waits).
// Distance-1 double buffer, counted vmcnt(8), exactly 2 raw s_barriers per
// K-tile. ds_read/MFMA scheduling left to the compiler (fine-grained lgkm)
// inside sched_barrier(0) walls. T2 swizzle both-sides as before.
// Race audit: each wave's ds_reads are lgkm-drained before its MFMAs, which
// precede its bar1 arrival; STAGE(t+1) (overwrites buf read at t-1) issues
// after bar1; ds_reads of buf[t] follow bar2 which follows all waves'
// vmcnt(8) (their t-loads complete, in-order per wave).
// ---------------------------------------------------------------------------
template<int KDIM>
__device__ __forceinline__ void gemm_mainloop(const ushort* __restrict__ A,
                                              const ushort* __restrict__ Bm,
                                              ushort* lds,
                                              int m0, int n0, int wid, int l,
                                              int wm, int wn,
                                              f32x4 (&acc)[4][4]) {
    constexpr int NT = KDIM / 64;
    const int r8   = l >> 3;                       // 0..7
    const int swzo = ((l & 7) * 16) ^ (r8 << 4);   // inverse-swizzled source byte
    const char* gA = (const char*)(A + (size_t)m0 * KDIM);
    const char* gB = (const char*)(Bm + (size_t)n0 * KDIM);

    // per-thread LDS frag pointers (swizzle folded; frag index -> imm offset)
    const int thr = (l & 15) * 128;
    const int f0  = (((l >> 4) * 16)      ^ ((l & 7) << 4));
    const int f1  = ((64 + (l >> 4) * 16) ^ ((l & 7) << 4));
    const char* pA0 = (const char*)lds + wm * 8192 + thr + f0;
    const char* pA1 = (const char*)lds + wm * 8192 + thr + f1;
    const char* pB0 = (const char*)lds + 16384 + wn * 8192 + thr + f0;
    const char* pB1 = (const char*)lds + 16384 + wn * 8192 + thr + f1;

    // staging: 8 chunks/thread (A rows j*32+wid*8+r8, then B same), LDS linear
    #define STAGE(T, BUF) do {                                                    \
        const size_t gb_ = (size_t)(T) * 128 + swzo;                              \
        char* lb_ = (char*)lds + (BUF) * 32768 + wid * 1024;                      \
        _Pragma("unroll")                                                         \
        for (int j_ = 0; j_ < 4; ++j_)                                            \
            gload16(gA + (size_t)(j_ * 32 + wid * 8 + r8) * (KDIM * 2) + gb_,     \
                    lb_ + j_ * 4096);                                             \
        _Pragma("unroll")                                                         \
        for (int j_ = 0; j_ < 4; ++j_)                                            \
            gload16(gB + (size_t)(j_ * 32 + wid * 8 + r8) * (KDIM * 2) + gb_,     \
                    lb_ + 16384 + j_ * 4096);                                     \
    } while (0)

    STAGE(0, 0);

    #pragma unroll 2
    for (int t = 0; t < NT; ++t) {
        __builtin_amdgcn_sched_barrier(0);
        __builtin_amdgcn_s_barrier();              // bar1: all prior reads done
        __builtin_amdgcn_sched_barrier(0);
        if (t + 1 < NT) {
            STAGE(t + 1, (t + 1) & 1);
            asm volatile("s_waitcnt vmcnt(8)" ::: "memory");   // tile t landed
        } else {
            asm volatile("s_waitcnt vmcnt(0)" ::: "memory");
        }
        __builtin_amdgcn_sched_barrier(0);
        __builtin_amdgcn_s_barrier();              // bar2: publish tile t
        __builtin_amdgcn_sched_barrier(0);

        const int bo = (t & 1) << 15;
        f16x8 Aa[4][2], Bb[4][2];
        #pragma unroll
        for (int i = 0; i < 4; ++i) {
            Aa[i][0] = *(const f16x8*)(pA0 + bo + i * 2048);
            Aa[i][1] = *(const f16x8*)(pA1 + bo + i * 2048);
        }
        #pragma unroll
        for (int j = 0; j < 4; ++j) {
            Bb[j][0] = *(const f16x8*)(pB0 + bo + j * 2048);
            Bb[j][1] = *(const f16x8*)(pB1 + bo + j * 2048);
        }
        __builtin_amdgcn_s_setprio(1);
        #pragma unroll
        for (int ks = 0; ks < 2; ++ks)
            #pragma unroll
            for (int i = 0; i < 4; ++i)
                #pragma unroll
                for (int j = 0; j < 4; ++j)
                    acc[i][j] = __builtin_amdgcn_mfma_f32_16x16x32_f16(
                        Aa[i][ks], Bb[j][ks], acc[i][j], 0, 0, 0);
        __builtin_amdgcn_s_setprio(0);
    }
    #undef STAGE
}

// 512 blocks: per XCD 8 M-panels x 8 N-panels (A fetched once chip-wide)
__device__ __forceinline__ void tile_map(int bid, int& m0, int& n0) {
    const int xcd = bid & 7;
    const int idx = bid >> 3;              // 0..63
    m0 = (xcd * 8 + (idx >> 3)) * 128;     // 64 M-tiles
    n0 = (idx & 7) * 128;                  // 8 N-tiles
}

// GEMM1: g_xs [8192][3072] x g_WpT[n][3072] -> pi*tanh(acc*2^-24 + bias) -> g_ph[b][n][s]
__global__ __launch_bounds__(256) void gemm1(const float* __restrict__ bias) {
    __shared__ ushort lds[2 * 16384];   // 64 KB
    const int tid = threadIdx.x;
    const int wid = tid >> 6, l = tid & 63;
    int m0, n0;
    tile_map(blockIdx.x, m0, n0);
    const int wm = wid >> 1, wn = wid & 1;

    f32x4 acc[4][4];
    #pragma unroll
    for (int i = 0; i < 4; ++i)
        #pragma unroll
        for (int j = 0; j < 4; ++j) acc[i][j] = (f32x4){0.f, 0.f, 0.f, 0.f};

    gemm_mainloop<K1_>(g_xs, g_WpT, lds, m0, n0, wid, l, wm, wn, acc);

    const int r4 = (l >> 4) * 4;
    const int cn = l & 15;
    #pragma unroll
    for (int i = 0; i < 4; ++i) {
        const int mg = m0 + wm * 64 + i * 16 + r4;
        const int bidx = mg >> 11;
        const int sg = mg & 2047;
        #pragma unroll
        for (int jj = 0; jj < 4; ++jj) {
            const int ng = n0 + wn * 64 + jj * 16 + cn;
            const float bb = bias[ng];
            float4 o;
            o.x = PI_ * tanhf(fmaf(acc[i][jj][0], INVSC2_, bb));
            o.y = PI_ * tanhf(fmaf(acc[i][jj][1], INVSC2_, bb));
            o.z = PI_ * tanhf(fmaf(acc[i][jj][2], INVSC2_, bb));
            o.w = PI_ * tanhf(fmaf(acc[i][jj][3], INVSC2_, bb));
            *(float4*)(g_ph + ((size_t)bidx * HN_ + ng) * S_ + sg) = o;
        }
    }
}

// GEMM3: g_phT [8192][1024] x g_WoT[d][1024] + bias -> Y [8192][1024] f32
__global__ __launch_bounds__(256) void gemm3(const float* __restrict__ bias,
                                             float* __restrict__ Y) {
    __shared__ ushort lds[2 * 16384];   // 64 KB
    const int tid = threadIdx.x;
    const int wid = tid >> 6, l = tid & 63;
    int m0, n0;
    tile_map(blockIdx.x, m0, n0);
    const int wm = wid >> 1, wn = wid & 1;

    f32x4 acc[4][4];
    #pragma unroll
    for (int i = 0; i < 4; ++i)
        #pragma unroll
        for (int j = 0; j < 4; ++j) acc[i][j] = (f32x4){0.f, 0.f, 0.f, 0.f};

    gemm_mainloop<K3_>(g_phT, g_WoT, lds, m0, n0, wid, l, wm, wn, acc);

    const int r4 = (l >> 4) * 4;
    const int cn = l & 15;
    #pragma unroll
    for (int i = 0; i < 4; ++i) {
        const int mg = m0 + wm * 64 + i * 16 + r4;
        #pragma unroll
        for (int jj = 0; jj < 4; ++jj) {
            const int ng = n0 + wn * 64 + jj * 16 + cn;
            const float bb = bias[ng];
            #pragma unroll
            for (int r = 0; r < 4; ++r)
                Y[(size_t)(mg + r) * D_ + ng] = acc[i][jj][r] + bb;
        }
    }
}

// ---------------------------------------------------------------------------
// Kuramoto (unchanged, verified): one wave per (b, hn), 10 iters in registers.
// ---------------------------------------------------------------------------
__global__ __launch_bounds__(256) void kuramoto(const int* __restrict__ mask,
                                                const float* __restrict__ natf,
                                                const float* __restrict__ coup) {
    const int wave = blockIdx.x * 4 + (threadIdx.x >> 6);
    const int lane = threadIdx.x & 63;
    const int b = wave >> 10;
    const int hn = wave & 1023;
    const int h = hn >> 7;

    const float wf = natf[hn];
    const float K = coup[h];

    const float* base = g_ph + ((size_t)b * HN_ + hn) * S_;

    float ph[32];
    #pragma unroll
    for (int i = 0; i < 8; ++i) {
        float4 v = *(const float4*)(base + i * 256 + lane * 4);
        ph[4 * i + 0] = v.x; ph[4 * i + 1] = v.y;
        ph[4 * i + 2] = v.z; ph[4 * i + 3] = v.w;
    }

    const int* mb = mask + b * S_;
    unsigned mbits = 0;
    #pragma unroll
    for (int i = 0; i < 8; ++i) {
        int4 mv = *(const int4*)(mb + i * 256 + lane * 4);
        mbits |= (mv.x != 0 ? 1u : 0u) << (4 * i + 0);
        mbits |= (mv.y != 0 ? 1u : 0u) << (4 * i + 1);
        mbits |= (mv.z != 0 ? 1u : 0u) << (4 * i + 2);
        mbits |= (mv.w != 0 ? 1u : 0u) << (4 * i + 3);
    }

    for (int it = 0; it < ITERS_; ++it) {
        float s[32], c[32];
        float ls = 0.f, lc = 0.f;
        #pragma unroll
        for (int i = 0; i < 32; ++i) {
            s[i] = __sinf(ph[i]);
            c[i] = __cosf(ph[i]);
            const float mf = (float)((mbits >> i) & 1u);
            ls = fmaf(mf, s[i], ls);
            lc = fmaf(mf, c[i], lc);
        }
        #pragma unroll
        for (int off = 32; off; off >>= 1) {
            ls += __shfl_xor(ls, off);
            lc += __shfl_xor(lc, off);
        }
        const float ms = ls * (1.f / 2048.f);
        const float mc = lc * (1.f / 2048.f);
        #pragma unroll
        for (int i = 0; i < 32; ++i) {
            const float dth = fmaf(K, fmaf(s[i], mc, -c[i] * ms), wf);
            float t = fmaf(DT_, dth, ph[i]) + PI_;
            t -= TWOPI_ * floorf(t * INV2PI_);
            ph[i] = t - PI_;
        }
    }

    ushort* ob = g_phh + ((size_t)b * HN_ + hn) * S_;
    #pragma unroll
    for (int i = 0; i < 8; ++i) {
        ushort4 o;
        o.x = f2h(ph[4 * i + 0]); o.y = f2h(ph[4 * i + 1]);
        o.z = f2h(ph[4 * i + 2]); o.w = f2h(ph[4 * i + 3]);
        *(ushort4*)(ob + i * 256 + lane * 4) = o;
    }
}

// ---------------------------------------------------------------------------
// g_phh [b][hn][s] fp16 -> g_phT [(b,s)][hn] fp16  (64x64 tiles, unchanged)
// ---------------------------------------------------------------------------
__global__ __launch_bounds__(256) void transpose_ph() {
    __shared__ ushort t[64][72];
    const int b = blockIdx.z;
    const int h0 = blockIdx.y * 64;
    const int s0 = blockIdx.x * 64;
    const int r = threadIdx.x >> 2;
    const int c = (threadIdx.x & 3) * 16;
    const ushort* src = g_phh + ((size_t)b * HN_ + h0 + r) * S_ + s0 + c;
    *(int4*)&t[r][c] = *(const int4*)src;
    *(int4*)&t[r][c + 8] = *(const int4*)(src + 8);
    __syncthreads();
    ushort o[16];
    #pragma unroll
    for (int j = 0; j < 16; ++j) o[j] = t[c + j][r];
    ushort* dst = g_phT + ((size_t)(b * S_ + s0 + r)) * HN_ + h0 + c;
    int4 o0, o1;
    o0.x = pack2(o[0], o[1]);   o0.y = pack2(o[2], o[3]);
    o0.z = pack2(o[4], o[5]);   o0.w = pack2(o[6], o[7]);
    o1.x = pack2(o[8], o[9]);   o1.y = pack2(o[10], o[11]);
    o1.z = pack2(o[12], o[13]); o1.w = pack2(o[14], o[15]);
    *(int4*)dst = o0;
    *(int4*)(dst + 8) = o1;
}

extern "C" void kernel_launch(void* const* d_in, const int* in_sizes, int n_in,
                              void* d_out, int out_size, void* d_ws, size_t ws_size,
                              hipStream_t stream) {
    const float* x    = (const float*)d_in[0];
    const int*   mask = (const int*)d_in[1];
    const float* Wp   = (const float*)d_in[2];
    const float* bp   = (const float*)d_in[3];
    const float* natf = (const float*)d_in[4];
    const float* coup = (const float*)d_in[5];
    const float* Wo   = (const float*)d_in[6];
    const float* bo   = (const float*)d_in[7];
    float* y = (float*)d_out;

    split_x  <<<dim3(8192),         256, 0, stream>>>(x);
    splitT_Wp<<<dim3(16, 16),       256, 0, stream>>>(Wp);
    castT_Wo <<<dim3(16, 16),       256, 0, stream>>>(Wo);
    gemm1    <<<dim3(512),          256, 0, stream>>>(bp);
    kuramoto <<<dim3(1024),         256, 0, stream>>>(mask, natf, coup);
    transpose_ph<<<dim3(32, 16, 4), 256, 0, stream>>>();
    gemm3    <<<dim3(512),          256, 0, stream>>>(bo, y);
}

// Round 8
// 166.168 us; speedup vs baseline: 1.0135x; 1.0135x over previous
//
#include <hip/hip_runtime.h>
#include <math.h>

#define S_ 2048
#define D_ 1024
#define HN_ 1024
#define B_ 4
#define M_ 8192
#define K1_ 3072
#define K3_ 1024
#define ITERS_ 10
#define DT_ 0.1f
#define PI_ 3.14159265358979323846f
#define TWOPI_ 6.28318530717958647692f
#define INV2PI_ 0.15915494309189533577f
#define SCALE_ 4096.0f
#define INVSC2_ (1.0f / 16777216.0f)   // 2^-24

typedef __attribute__((ext_vector_type(8))) _Float16 f16x8;
typedef __attribute__((ext_vector_type(4))) float f32x4;

// static scratch
__device__ ushort g_xs [(size_t)M_ * K1_];      // x split [a|a|b] fp16, scaled 4096
__device__ ushort g_WpT[(size_t)HN_ * K1_];     // Wp^T split [a|b|a] fp16, scaled 4096
__device__ float  g_ph [(size_t)B_ * HN_ * S_]; // phases f32 [b][hn][s]
__device__ ushort g_phh[(size_t)B_ * HN_ * S_]; // final phases fp16 [b][hn][s]
__device__ ushort g_phT[(size_t)M_ * HN_];      // phases fp16 [(b,s)][hn]
__device__ ushort g_WoT[(size_t)D_ * HN_];      // Wo^T fp16 [d][hn] (unscaled)

__device__ __forceinline__ ushort f2h(float f) {
    union { _Float16 h; ushort u; } v; v.h = (_Float16)f; return v.u;
}
__device__ __forceinline__ void split2s(float x, ushort& A, ushort& Bc) {
    const float xs = x * SCALE_;
    union { _Float16 h; ushort u; } va, vb;
    va.h = (_Float16)xs;
    const float r = xs - (float)va.h;   // exact
    vb.h = (_Float16)r;
    A = va.u; Bc = vb.u;
}
__device__ __forceinline__ void gload16(const void* g, void* l) {
    __builtin_amdgcn_global_load_lds(
        (const __attribute__((address_space(1))) void*)g,
        (__attribute__((address_space(3))) void*)l, 16, 0, 0);
}
__device__ __forceinline__ int pack2(ushort a, ushort b) {
    return (int)(unsigned)a | ((int)(unsigned)b << 16);
}

// ---------------------------------------------------------------------------
// prep kernels (unchanged, verified)
// ---------------------------------------------------------------------------
__global__ __launch_bounds__(256) void split_x(const float* __restrict__ X) {
    const int idx = blockIdx.x * 256 + threadIdx.x;
    const float4 v = ((const float4*)X)[idx];
    const int m  = idx >> 8;
    const int k4 = (idx & 255) * 4;
    ushort a[4], b[4];
    split2s(v.x, a[0], b[0]);
    split2s(v.y, a[1], b[1]);
    split2s(v.z, a[2], b[2]);
    split2s(v.w, a[3], b[3]);
    ushort* row = g_xs + (size_t)m * K1_ + k4;
    int2 oa; oa.x = pack2(a[0], a[1]); oa.y = pack2(a[2], a[3]);
    int2 ob; ob.x = pack2(b[0], b[1]); ob.y = pack2(b[2], b[3]);
    *(int2*)(row)        = oa;
    *(int2*)(row + 1024) = oa;
    *(int2*)(row + 2048) = ob;
}

__global__ __launch_bounds__(256) void splitT_Wp(const float* __restrict__ Wp) {
    __shared__ float t[64][68];
    const int k0 = blockIdx.x * 64;
    const int n0 = blockIdx.y * 64;
    const int r = threadIdx.x >> 2;
    const int c = (threadIdx.x & 3) * 16;
    const float* src = Wp + (size_t)(k0 + r) * HN_ + n0 + c;
    #pragma unroll
    for (int q = 0; q < 4; ++q)
        *(float4*)&t[r][c + 4 * q] = ((const float4*)src)[q];
    __syncthreads();
    ushort ha[16], hb[16];
    #pragma unroll
    for (int j = 0; j < 16; ++j)
        split2s(t[c + j][r], ha[j], hb[j]);
    int4 a0, a1, b0, b1;
    a0.x = pack2(ha[0], ha[1]);   a0.y = pack2(ha[2], ha[3]);
    a0.z = pack2(ha[4], ha[5]);   a0.w = pack2(ha[6], ha[7]);
    a1.x = pack2(ha[8], ha[9]);   a1.y = pack2(ha[10], ha[11]);
    a1.z = pack2(ha[12], ha[13]); a1.w = pack2(ha[14], ha[15]);
    b0.x = pack2(hb[0], hb[1]);   b0.y = pack2(hb[2], hb[3]);
    b0.z = pack2(hb[4], hb[5]);   b0.w = pack2(hb[6], hb[7]);
    b1.x = pack2(hb[8], hb[9]);   b1.y = pack2(hb[10], hb[11]);
    b1.z = pack2(hb[12], hb[13]); b1.w = pack2(hb[14], hb[15]);
    ushort* dst = g_WpT + (size_t)(n0 + r) * K1_ + k0 + c;
    *(int4*)(dst)            = a0; *(int4*)(dst + 8)        = a1;
    *(int4*)(dst + 1024)     = b0; *(int4*)(dst + 1032)     = b1;
    *(int4*)(dst + 2048)     = a0; *(int4*)(dst + 2056)     = a1;
}

__global__ __launch_bounds__(256) void castT_Wo(const float* __restrict__ Wo) {
    __shared__ float t[64][68];
    const int k0 = blockIdx.x * 64;   // hn
    const int n0 = blockIdx.y * 64;   // d
    const int r = threadIdx.x >> 2;
    const int c = (threadIdx.x & 3) * 16;
    const float* src = Wo + (size_t)(k0 + r) * D_ + n0 + c;
    #pragma unroll
    for (int q = 0; q < 4; ++q)
        *(float4*)&t[r][c + 4 * q] = ((const float4*)src)[q];
    __syncthreads();
    ushort h[16];
    #pragma unroll
    for (int j = 0; j < 16; ++j) h[j] = f2h(t[c + j][r]);
    ushort* dst = g_WoT + (size_t)(n0 + r) * HN_ + k0 + c;
    int4 o0, o1;
    o0.x = pack2(h[0], h[1]);   o0.y = pack2(h[2], h[3]);
    o0.z = pack2(h[4], h[5]);   o0.w = pack2(h[6], h[7]);
    o1.x = pack2(h[8], h[9]);   o1.y = pack2(h[10], h[11]);
    o1.z = pack2(h[12], h[13]); o1.w = pack2(h[14], h[15]);
    *(int4*)dst = o0;
    *(int4*)(dst + 8) = o1;
}

// ---------------------------------------------------------------------------
// MFMA main loop, BM=128 x BN=128, BK=64, 8 waves (2M x 4N), 512 threads.
// Per-wave output 64x32 (acc 4x2). LDS: 2 x 32KB double buffer = 64KB ->
// 2 blocks/CU = 16 waves/CU = 4 waves/SIMD (the round-8 lever: inter-wave
// latency hiding). 2 raw s_barriers per K-tile, counted vmcnt(4), compiler
// schedules ds_read/MFMA inside sched_barrier(0) walls. T2 swizzle both-sides.
// Race audit: each wave's ds_reads are lgkm-drained before its MFMAs (all
// reads consumed), which precede its bar1 arrival; STAGE(t+1) (overwrites
// buf read at t-1) issues after bar1; ds_reads of buf[t] follow bar2 which
// follows all waves' vmcnt(4) (tile-t loads complete, in-order per wave).
// ---------------------------------------------------------------------------
template<int KDIM>
__device__ __forceinline__ void gemm_mainloop(const ushort* __restrict__ A,
                                              const ushort* __restrict__ Bm,
                                              ushort* lds,
                                              int m0, int n0, int wid, int l,
                                              int wm, int wn,
                                              f32x4 (&acc)[4][2]) {
    constexpr int NT = KDIM / 64;
    const int r8   = l >> 3;                       // 0..7
    const int swzo = ((l & 7) * 16) ^ (r8 << 4);   // inverse-swizzled source byte
    const char* gA = (const char*)(A + (size_t)m0 * KDIM);
    const char* gB = (const char*)(Bm + (size_t)n0 * KDIM);

    // per-lane LDS frag addressing: row = base + l15, slot = kb ^ ((l15&7)<<4)
    const int l15 = l & 15;
    const int xk  = (l15 & 7) << 4;
    const int sl0 = (((l >> 4) * 16)) ^ xk;        // ks=0 slot
    const int sl1 = (64 + ((l >> 4) * 16)) ^ xk;   // ks=1 slot
    const char* pA = (const char*)lds + (wm * 64 + l15) * 128;
    const char* pB = (const char*)lds + 16384 + (wn * 32 + l15) * 128;

    // staging: 4 chunks/thread-wave (A rows wid*16+{0,8}+r8, B same), LDS linear
    #define STAGE(T, BUF) do {                                                    \
        const size_t gb_ = (size_t)(T) * 128 + swzo;                              \
        char* lb_ = (char*)lds + (BUF) * 32768 + wid * 2048;                      \
        gload16(gA + (size_t)(wid * 16 + r8)     * (KDIM * 2) + gb_, lb_);        \
        gload16(gA + (size_t)(wid * 16 + 8 + r8) * (KDIM * 2) + gb_, lb_ + 1024); \
        gload16(gB + (size_t)(wid * 16 + r8)     * (KDIM * 2) + gb_, lb_ + 16384);\
        gload16(gB + (size_t)(wid * 16 + 8 + r8) * (KDIM * 2) + gb_, lb_ + 16384 + 1024); \
    } while (0)

    STAGE(0, 0);

    #pragma unroll 2
    for (int t = 0; t < NT; ++t) {
        __builtin_amdgcn_sched_barrier(0);
        __builtin_amdgcn_s_barrier();              // bar1: all prior reads done
        __builtin_amdgcn_sched_barrier(0);
        if (t + 1 < NT) {
            STAGE(t + 1, (t + 1) & 1);
            asm volatile("s_waitcnt vmcnt(4)" ::: "memory");   // tile t landed
        } else {
            asm volatile("s_waitcnt vmcnt(0)" ::: "memory");
        }
        __builtin_amdgcn_sched_barrier(0);
        __builtin_amdgcn_s_barrier();              // bar2: publish tile t
        __builtin_amdgcn_sched_barrier(0);

        const int bo = (t & 1) << 15;
        f16x8 Aa[4][2], Bb[2][2];
        #pragma unroll
        for (int i = 0; i < 4; ++i) {
            Aa[i][0] = *(const f16x8*)(pA + bo + i * 2048 + sl0);
            Aa[i][1] = *(const f16x8*)(pA + bo + i * 2048 + sl1);
        }
        #pragma unroll
        for (int j = 0; j < 2; ++j) {
            Bb[j][0] = *(const f16x8*)(pB + bo + j * 2048 + sl0);
            Bb[j][1] = *(const f16x8*)(pB + bo + j * 2048 + sl1);
        }
        __builtin_amdgcn_s_setprio(1);
        #pragma unroll
        for (int ks = 0; ks < 2; ++ks)
            #pragma unroll
            for (int i = 0; i < 4; ++i)
                #pragma unroll
                for (int j = 0; j < 2; ++j)
                    acc[i][j] = __builtin_amdgcn_mfma_f32_16x16x32_f16(
                        Aa[i][ks], Bb[j][ks], acc[i][j], 0, 0, 0);
        __builtin_amdgcn_s_setprio(0);
    }
    #undef STAGE
}

// 512 blocks: per XCD 8 M-panels x 8 N-panels (A fetched once chip-wide)
__device__ __forceinline__ void tile_map(int bid, int& m0, int& n0) {
    const int xcd = bid & 7;
    const int idx = bid >> 3;              // 0..63
    m0 = (xcd * 8 + (idx >> 3)) * 128;     // 64 M-tiles
    n0 = (idx & 7) * 128;                  // 8 N-tiles
}

// GEMM1: g_xs [8192][3072] x g_WpT[n][3072] -> pi*tanh(acc*2^-24 + bias) -> g_ph[b][n][s]
__global__ __launch_bounds__(512, 4) void gemm1(const float* __restrict__ bias) {
    __shared__ ushort lds[2 * 16384];   // 64 KB
    const int tid = threadIdx.x;
    const int wid = tid >> 6, l = tid & 63;
    int m0, n0;
    tile_map(blockIdx.x, m0, n0);
    const int wm = wid >> 2, wn = wid & 3;

    f32x4 acc[4][2];
    #pragma unroll
    for (int i = 0; i < 4; ++i)
        #pragma unroll
        for (int j = 0; j < 2; ++j) acc[i][j] = (f32x4){0.f, 0.f, 0.f, 0.f};

    gemm_mainloop<K1_>(g_xs, g_WpT, lds, m0, n0, wid, l, wm, wn, acc);

    const int r4 = (l >> 4) * 4;
    const int cn = l & 15;
    #pragma unroll
    for (int i = 0; i < 4; ++i) {
        const int mg = m0 + wm * 64 + i * 16 + r4;
        const int bidx = mg >> 11;
        const int sg = mg & 2047;
        #pragma unroll
        for (int jj = 0; jj < 2; ++jj) {
            const int ng = n0 + wn * 32 + jj * 16 + cn;
            const float bb = bias[ng];
            float4 o;
            o.x = PI_ * tanhf(fmaf(acc[i][jj][0], INVSC2_, bb));
            o.y = PI_ * tanhf(fmaf(acc[i][jj][1], INVSC2_, bb));
            o.z = PI_ * tanhf(fmaf(acc[i][jj][2], INVSC2_, bb));
            o.w = PI_ * tanhf(fmaf(acc[i][jj][3], INVSC2_, bb));
            *(float4*)(g_ph + ((size_t)bidx * HN_ + ng) * S_ + sg) = o;
        }
    }
}

// GEMM3: g_phT [8192][1024] x g_WoT[d][1024] + bias -> Y [8192][1024] f32
__global__ __launch_bounds__(512, 4) void gemm3(const float* __restrict__ bias,
                                                float* __restrict__ Y) {
    __shared__ ushort lds[2 * 16384];   // 64 KB
    const int tid = threadIdx.x;
    const int wid = tid >> 6, l = tid & 63;
    int m0, n0;
    tile_map(blockIdx.x, m0, n0);
    const int wm = wid >> 2, wn = wid & 3;

    f32x4 acc[4][2];
    #pragma unroll
    for (int i = 0; i < 4; ++i)
        #pragma unroll
        for (int j = 0; j < 2; ++j) acc[i][j] = (f32x4){0.f, 0.f, 0.f, 0.f};

    gemm_mainloop<K3_>(g_phT, g_WoT, lds, m0, n0, wid, l, wm, wn, acc);

    const int r4 = (l >> 4) * 4;
    const int cn = l & 15;
    #pragma unroll
    for (int i = 0; i < 4; ++i) {
        const int mg = m0 + wm * 64 + i * 16 + r4;
        #pragma unroll
        for (int jj = 0; jj < 2; ++jj) {
            const int ng = n0 + wn * 32 + jj * 16 + cn;
            const float bb = bias[ng];
            #pragma unroll
            for (int r = 0; r < 4; ++r)
                Y[(size_t)(mg + r) * D_ + ng] = acc[i][jj][r] + bb;
        }
    }
}

// ---------------------------------------------------------------------------
// Kuramoto (unchanged, verified): one wave per (b, hn), 10 iters in registers.
// ---------------------------------------------------------------------------
__global__ __launch_bounds__(256) void kuramoto(const int* __restrict__ mask,
                                                const float* __restrict__ natf,
                                                const float* __restrict__ coup) {
    const int wave = blockIdx.x * 4 + (threadIdx.x >> 6);
    const int lane = threadIdx.x & 63;
    const int b = wave >> 10;
    const int hn = wave & 1023;
    const int h = hn >> 7;

    const float wf = natf[hn];
    const float K = coup[h];

    const float* base = g_ph + ((size_t)b * HN_ + hn) * S_;

    float ph[32];
    #pragma unroll
    for (int i = 0; i < 8; ++i) {
        float4 v = *(const float4*)(base + i * 256 + lane * 4);
        ph[4 * i + 0] = v.x; ph[4 * i + 1] = v.y;
        ph[4 * i + 2] = v.z; ph[4 * i + 3] = v.w;
    }

    const int* mb = mask + b * S_;
    unsigned mbits = 0;
    #pragma unroll
    for (int i = 0; i < 8; ++i) {
        int4 mv = *(const int4*)(mb + i * 256 + lane * 4);
        mbits |= (mv.x != 0 ? 1u : 0u) << (4 * i + 0);
        mbits |= (mv.y != 0 ? 1u : 0u) << (4 * i + 1);
        mbits |= (mv.z != 0 ? 1u : 0u) << (4 * i + 2);
        mbits |= (mv.w != 0 ? 1u : 0u) << (4 * i + 3);
    }

    for (int it = 0; it < ITERS_; ++it) {
        float s[32], c[32];
        float ls = 0.f, lc = 0.f;
        #pragma unroll
        for (int i = 0; i < 32; ++i) {
            s[i] = __sinf(ph[i]);
            c[i] = __cosf(ph[i]);
            const float mf = (float)((mbits >> i) & 1u);
            ls = fmaf(mf, s[i], ls);
            lc = fmaf(mf, c[i], lc);
        }
        #pragma unroll
        for (int off = 32; off; off >>= 1) {
            ls += __shfl_xor(ls, off);
            lc += __shfl_xor(lc, off);
        }
        const float ms = ls * (1.f / 2048.f);
        const float mc = lc * (1.f / 2048.f);
        #pragma unroll
        for (int i = 0; i < 32; ++i) {
            const float dth = fmaf(K, fmaf(s[i], mc, -c[i] * ms), wf);
            float t = fmaf(DT_, dth, ph[i]) + PI_;
            t -= TWOPI_ * floorf(t * INV2PI_);
            ph[i] = t - PI_;
        }
    }

    ushort* ob = g_phh + ((size_t)b * HN_ + hn) * S_;
    #pragma unroll
    for (int i = 0; i < 8; ++i) {
        ushort4 o;
        o.x = f2h(ph[4 * i + 0]); o.y = f2h(ph[4 * i + 1]);
        o.z = f2h(ph[4 * i + 2]); o.w = f2h(ph[4 * i + 3]);
        *(ushort4*)(ob + i * 256 + lane * 4) = o;
    }
}

// ---------------------------------------------------------------------------
// g_phh [b][hn][s] fp16 -> g_phT [(b,s)][hn] fp16  (64x64 tiles, unchanged)
// ---------------------------------------------------------------------------
__global__ __launch_bounds__(256) void transpose_ph() {
    __shared__ ushort t[64][72];
    const int b = blockIdx.z;
    const int h0 = blockIdx.y * 64;
    const int s0 = blockIdx.x * 64;
    const int r = threadIdx.x >> 2;
    const int c = (threadIdx.x & 3) * 16;
    const ushort* src = g_phh + ((size_t)b * HN_ + h0 + r) * S_ + s0 + c;
    *(int4*)&t[r][c] = *(const int4*)src;
    *(int4*)&t[r][c + 8] = *(const int4*)(src + 8);
    __syncthreads();
    ushort o[16];
    #pragma unroll
    for (int j = 0; j < 16; ++j) o[j] = t[c + j][r];
    ushort* dst = g_phT + ((size_t)(b * S_ + s0 + r)) * HN_ + h0 + c;
    int4 o0, o1;
    o0.x = pack2(o[0], o[1]);   o0.y = pack2(o[2], o[3]);
    o0.z = pack2(o[4], o[5]);   o0.w = pack2(o[6], o[7]);
    o1.x = pack2(o[8], o[9]);   o1.y = pack2(o[10], o[11]);
    o1.z = pack2(o[12], o[13]); o1.w = pack2(o[14], o[15]);
    *(int4*)dst = o0;
    *(int4*)(dst + 8) = o1;
}

extern "C" void kernel_launch(void* const* d_in, const int* in_sizes, int n_in,
                              void* d_out, int out_size, void* d_ws, size_t ws_size,
                              hipStream_t stream) {
    const float* x    = (const float*)d_in[0];
    const int*   mask = (const int*)d_in[1];
    const float* Wp   = (const float*)d_in[2];
    const float* bp   = (const float*)d_in[3];
    const float* natf = (const float*)d_in[4];
    const float* coup = (const float*)d_in[5];
    const float* Wo   = (const float*)d_in[6];
    const float* bo   = (const float*)d_in[7];
    float* y = (float*)d_out;

    split_x  <<<dim3(8192),         256, 0, stream>>>(x);
    splitT_Wp<<<dim3(16, 16),       256, 0, stream>>>(Wp);
    castT_Wo <<<dim3(16, 16),       256, 0, stream>>>(Wo);
    gemm1    <<<dim3(512),          512, 0, stream>>>(bp);
    kuramoto <<<dim3(1024),         256, 0, stream>>>(mask, natf, coup);
    transpose_ph<<<dim3(32, 16, 4), 256, 0, stream>>>();
    gemm3    <<<dim3(512),          512, 0, stream>>>(bo, y);
}